// Round 1
// baseline (420.167 us; speedup 1.0000x reference)
//
#include <hip/hip_runtime.h>

#define HIDDEN 2048
#define EXPERTS 64
#define T_TOTAL 8192
#define CH 16

// ---------------------------------------------------------------------------
// Kernel 1: currents[t][e] = sum_k A[t][k] * W[k][e]
// block = 256 threads (4 waves); each wave: lane = expert e, 8 rows; block = 32 rows.
// A-row loads are wave-broadcast (same addr all lanes -> 1 txn, L1-hit);
// W loads are fully coalesced (64 lanes * 4B = 256B).
// ---------------------------------------------------------------------------
__global__ __launch_bounds__(256) void snn_gemm(const float* __restrict__ A,
                                                const float* __restrict__ W,
                                                float* __restrict__ C) {
    const int lane = threadIdx.x & 63;
    const int wv   = threadIdx.x >> 6;
    const long row0 = (long)blockIdx.x * 32 + (long)wv * 8;
    const float* a0 = A + row0 * HIDDEN;

    float acc[8];
#pragma unroll
    for (int r = 0; r < 8; ++r) acc[r] = 0.0f;

    for (int k = 0; k < HIDDEN; k += 4) {
        const float w0 = W[(k + 0) * EXPERTS + lane];
        const float w1 = W[(k + 1) * EXPERTS + lane];
        const float w2 = W[(k + 2) * EXPERTS + lane];
        const float w3 = W[(k + 3) * EXPERTS + lane];
#pragma unroll
        for (int r = 0; r < 8; ++r) {
            const float4 a = *reinterpret_cast<const float4*>(a0 + (long)r * HIDDEN + k);
            acc[r] = fmaf(a.x, w0, acc[r]);
            acc[r] = fmaf(a.y, w1, acc[r]);
            acc[r] = fmaf(a.z, w2, acc[r]);
            acc[r] = fmaf(a.w, w3, acc[r]);
        }
    }

#pragma unroll
    for (int r = 0; r < 8; ++r)
        C[(row0 + r) * EXPERTS + lane] = acc[r];
}

// ---------------------------------------------------------------------------
// Kernel 2: sequential LIF scan. One wave, lane = expert.
// Stores PRE-RESET membrane potential mp_pre[t][e] into d_out; spike flags are
// recomputed in kernel 3 as (mp_pre > 1). Double-buffered register prefetch of
// currents keeps HBM/L2 latency off the loop-carried chain.
// fp contract(off): match reference's unfused  mp*LEAK  then  + term  rounding.
// ---------------------------------------------------------------------------
__global__ __launch_bounds__(64) void snn_scan(const float* __restrict__ cur,
                                               float* __restrict__ mp_out) {
#pragma clang fp contract(off)
    const int e = threadIdx.x;   // 0..63
    float mp = 0.0f, refr = 0.0f;

    float ca[CH], cb[CH];

#pragma unroll
    for (int j = 0; j < CH; ++j) ca[j] = cur[j * EXPERTS + e] * 0.1f;

    for (int t0 = 0; t0 < T_TOTAL; t0 += 2 * CH) {
        // prefetch chunk B (t0+CH .. t0+2CH-1)  -- always in range (T%32==0)
#pragma unroll
        for (int j = 0; j < CH; ++j)
            cb[j] = cur[(t0 + CH + j) * EXPERTS + e] * 0.1f;

        // process chunk A at t0
#pragma unroll
        for (int j = 0; j < CH; ++j) {
            const float term   = (refr <= 0.0f) ? ca[j] : 0.0f;
            const float mp_lk  = mp * 0.9f;
            const float mp_pre = mp_lk + term;
            mp_out[(t0 + j) * EXPERTS + e] = mp_pre;
            const bool  spike  = mp_pre > 1.0f;
            mp = spike ? 0.0f : mp_pre;
            const float rdec = fmaxf(refr - 0.1f, 0.0f);
            refr = spike ? 1.0f : rdec;
        }

        // prefetch chunk A for t0+2CH
        if (t0 + 2 * CH < T_TOTAL) {
#pragma unroll
            for (int j = 0; j < CH; ++j)
                ca[j] = cur[(t0 + 2 * CH + j) * EXPERTS + e] * 0.1f;
        }

        // process chunk B at t0+CH
#pragma unroll
        for (int j = 0; j < CH; ++j) {
            const float term   = (refr <= 0.0f) ? cb[j] : 0.0f;
            const float mp_lk  = mp * 0.9f;
            const float mp_pre = mp_lk + term;
            mp_out[(t0 + CH + j) * EXPERTS + e] = mp_pre;
            const bool  spike  = mp_pre > 1.0f;
            mp = spike ? 0.0f : mp_pre;
            const float rdec = fmaxf(refr - 0.1f, 0.0f);
            refr = spike ? 1.0f : rdec;
        }
    }
}

// ---------------------------------------------------------------------------
// Kernel 3: routing softmax, in-place on d_out (one wave per timestep row).
// spike branch: softmax of {0,1} vector = {1, e^-1}/denom with max-subtraction,
// exactly as jax.nn.softmax does. sub-threshold: standard stable softmax(mp).
// ---------------------------------------------------------------------------
__global__ __launch_bounds__(256) void snn_softmax(float* __restrict__ io) {
    const int  lane = threadIdx.x & 63;
    const int  wv   = threadIdx.x >> 6;
    const long t    = (long)blockIdx.x * 4 + wv;

    const float v = io[t * EXPERTS + lane];
    const bool spike = v > 1.0f;
    const unsigned long long ball = __ballot(spike);

    float out;
    if (ball != 0ull) {
        const int   n   = __popcll(ball);
        const float em1 = expf(-1.0f);
        const float denom = (float)n + (float)(EXPERTS - n) * em1;
        out = spike ? (1.0f / denom) : (em1 / denom);
    } else {
        float m = v;
#pragma unroll
        for (int off = 32; off >= 1; off >>= 1)
            m = fmaxf(m, __shfl_xor(m, off, 64));
        const float p = expf(v - m);
        float s = p;
#pragma unroll
        for (int off = 32; off >= 1; off >>= 1)
            s += __shfl_xor(s, off, 64);
        out = p / s;
    }
    io[t * EXPERTS + lane] = out;
}

// ---------------------------------------------------------------------------
extern "C" void kernel_launch(void* const* d_in, const int* in_sizes, int n_in,
                              void* d_out, int out_size, void* d_ws, size_t ws_size,
                              hipStream_t stream) {
    const float* hs = (const float*)d_in[0];   // [4,2048,2048] f32
    const float* w  = (const float*)d_in[1];   // [2048,64] f32
    float* out = (float*)d_out;                // [4,2048,64] f32
    float* cur = (float*)d_ws;                 // currents scratch: 8192*64*4 = 2 MB

    snn_gemm<<<dim3(T_TOTAL / 32), dim3(256), 0, stream>>>(hs, w, cur);
    snn_scan<<<dim3(1), dim3(64), 0, stream>>>(cur, out);
    snn_softmax<<<dim3(T_TOTAL / 4), dim3(256), 0, stream>>>(out);
}

// Round 2
// 221.324 us; speedup vs baseline: 1.8984x; 1.8984x over previous
//
#include <hip/hip_runtime.h>

#define HIDDEN 2048
#define EXPERTS 64
#define T_TOTAL 8192

// ---------------- GEMM: currents[t][e] = sum_k A[t][k]*W[k][e] ----------------
#define GROWS 4                 // rows per wave
#define GBLK_ROWS (4 * GROWS)   // 16 rows per 256-thread block -> 512 blocks, 2 waves/SIMD

__global__ __launch_bounds__(256) void snn_gemm(const float* __restrict__ A,
                                                const float* __restrict__ W,
                                                float* __restrict__ C) {
    const int lane = threadIdx.x & 63;
    const int wv   = threadIdx.x >> 6;
    const long row0 = (long)blockIdx.x * GBLK_ROWS + (long)wv * GROWS;
    const float* a0 = A + row0 * HIDDEN;
    const float* wp = W + lane;

    float acc[GROWS];
#pragma unroll
    for (int r = 0; r < GROWS; ++r) acc[r] = 0.0f;

    float  wA[8], wB[8];
    float4 aA[GROWS * 2], aB[GROWS * 2];

    // preload group k=0
#pragma unroll
    for (int i = 0; i < 8; ++i) wA[i] = wp[i * EXPERTS];
#pragma unroll
    for (int r = 0; r < GROWS; ++r)
#pragma unroll
        for (int j = 0; j < 2; ++j)
            aA[r * 2 + j] = *reinterpret_cast<const float4*>(a0 + (long)r * HIDDEN + j * 4);

    for (int k = 0; k < HIDDEN; k += 16) {
        // prefetch group k+8
#pragma unroll
        for (int i = 0; i < 8; ++i) wB[i] = wp[(k + 8 + i) * EXPERTS];
#pragma unroll
        for (int r = 0; r < GROWS; ++r)
#pragma unroll
            for (int j = 0; j < 2; ++j)
                aB[r * 2 + j] = *reinterpret_cast<const float4*>(a0 + (long)r * HIDDEN + (k + 8) + j * 4);
        // fma group k
#pragma unroll
        for (int r = 0; r < GROWS; ++r)
#pragma unroll
            for (int j = 0; j < 2; ++j) {
                const float4 a = aA[r * 2 + j];
                acc[r] = fmaf(a.x, wA[j * 4 + 0], acc[r]);
                acc[r] = fmaf(a.y, wA[j * 4 + 1], acc[r]);
                acc[r] = fmaf(a.z, wA[j * 4 + 2], acc[r]);
                acc[r] = fmaf(a.w, wA[j * 4 + 3], acc[r]);
            }
        // prefetch group k+16
        if (k + 16 < HIDDEN) {
#pragma unroll
            for (int i = 0; i < 8; ++i) wA[i] = wp[(k + 16 + i) * EXPERTS];
#pragma unroll
            for (int r = 0; r < GROWS; ++r)
#pragma unroll
                for (int j = 0; j < 2; ++j)
                    aA[r * 2 + j] = *reinterpret_cast<const float4*>(a0 + (long)r * HIDDEN + (k + 16) + j * 4);
        }
        // fma group k+8
#pragma unroll
        for (int r = 0; r < GROWS; ++r)
#pragma unroll
            for (int j = 0; j < 2; ++j) {
                const float4 a = aB[r * 2 + j];
                acc[r] = fmaf(a.x, wB[j * 4 + 0], acc[r]);
                acc[r] = fmaf(a.y, wB[j * 4 + 1], acc[r]);
                acc[r] = fmaf(a.z, wB[j * 4 + 2], acc[r]);
                acc[r] = fmaf(a.w, wB[j * 4 + 3], acc[r]);
            }
    }
#pragma unroll
    for (int r = 0; r < GROWS; ++r)
        C[(row0 + r) * EXPERTS + lane] = acc[r];
}

// ---------------- Scan: waveform relaxation over 16 chunks x 512 steps ----------------
#define NCHUNK 16
#define CSTEPS (T_TOTAL / NCHUNK)   // 512
#define KITER  4
#define PF     32                   // prefetch depth (steps)

__global__ __launch_bounds__(64) void snn_scan_wfr(const float* __restrict__ cur,
                                                   float* __restrict__ mp_out,
                                                   float* __restrict__ states,
                                                   int* __restrict__ flags) {
#pragma clang fp contract(off)
    __shared__ float smp[CSTEPS * EXPERTS];   // 128 KB: pre-reset membrane trajectory
    const int e = threadIdx.x;                // lane = expert
    const int w = blockIdx.x;                 // chunk
    const float* cbase = cur + (long)w * CSTEPS * EXPERTS + e;

    for (int k = 1; k <= KITER; ++k) {
        float mp = 0.0f, refr = 0.0f;
        if (w > 0 && k > 1) {
            const int s = (k - 2) * NCHUNK + (w - 1);
            if (e == 0) {
                while (__hip_atomic_load(&flags[s], __ATOMIC_ACQUIRE, __HIP_MEMORY_SCOPE_AGENT) == 0)
                    __builtin_amdgcn_s_sleep(8);
            }
            __threadfence();
            mp   = __hip_atomic_load(&states[s * 2 * EXPERTS + e], __ATOMIC_RELAXED, __HIP_MEMORY_SCOPE_AGENT);
            refr = __hip_atomic_load(&states[s * 2 * EXPERTS + EXPERTS + e], __ATOMIC_RELAXED, __HIP_MEMORY_SCOPE_AGENT);
        }

        float ca[PF], cb[PF];
#pragma unroll
        for (int j = 0; j < PF; ++j) ca[j] = cbase[j * EXPERTS] * 0.1f;

        for (int t0 = 0; t0 < CSTEPS; t0 += 2 * PF) {
#pragma unroll
            for (int j = 0; j < PF; ++j) cb[j] = cbase[(t0 + PF + j) * EXPERTS] * 0.1f;
#pragma unroll
            for (int j = 0; j < PF; ++j) {
                const float term   = (refr <= 0.0f) ? ca[j] : 0.0f;
                const float mp_pre = mp * 0.9f + term;
                smp[(t0 + j) * EXPERTS + e] = mp_pre;
                const bool spike = mp_pre > 1.0f;
                mp = spike ? 0.0f : mp_pre;
                const float rdec = fmaxf(refr - 0.1f, 0.0f);
                refr = spike ? 1.0f : rdec;
            }
            if (t0 + 2 * PF < CSTEPS) {
#pragma unroll
                for (int j = 0; j < PF; ++j) ca[j] = cbase[(t0 + 2 * PF + j) * EXPERTS] * 0.1f;
            }
#pragma unroll
            for (int j = 0; j < PF; ++j) {
                const float term   = (refr <= 0.0f) ? cb[j] : 0.0f;
                const float mp_pre = mp * 0.9f + term;
                smp[(t0 + PF + j) * EXPERTS + e] = mp_pre;
                const bool spike = mp_pre > 1.0f;
                mp = spike ? 0.0f : mp_pre;
                const float rdec = fmaxf(refr - 0.1f, 0.0f);
                refr = spike ? 1.0f : rdec;
            }
        }

        // publish boundary state for chunk w+1's next iteration
        if (k < KITER && w < NCHUNK - 1) {
            const int s2 = (k - 1) * NCHUNK + w;
            __hip_atomic_store(&states[s2 * 2 * EXPERTS + e], mp, __ATOMIC_RELAXED, __HIP_MEMORY_SCOPE_AGENT);
            __hip_atomic_store(&states[s2 * 2 * EXPERTS + EXPERTS + e], refr, __ATOMIC_RELAXED, __HIP_MEMORY_SCOPE_AGENT);
            __threadfence();
            if (e == 0)
                __hip_atomic_store(&flags[s2], 1, __ATOMIC_RELEASE, __HIP_MEMORY_SCOPE_AGENT);
        }
    }

    // bulk-copy LDS trajectory -> global (coalesced float4)
    float4* o4 = reinterpret_cast<float4*>(mp_out + (long)w * CSTEPS * EXPERTS);
    const float4* s4 = reinterpret_cast<const float4*>(smp);
#pragma unroll 4
    for (int i = threadIdx.x; i < CSTEPS * EXPERTS / 4; i += 64)
        o4[i] = s4[i];
}

// ---------------- Routing softmax, in-place on d_out ----------------
__global__ __launch_bounds__(256) void snn_softmax(float* __restrict__ io) {
    const int  lane = threadIdx.x & 63;
    const int  wv   = threadIdx.x >> 6;
    const long t    = (long)blockIdx.x * 4 + wv;

    const float v = io[t * EXPERTS + lane];
    const bool spike = v > 1.0f;
    const unsigned long long ball = __ballot(spike);

    float out;
    if (ball != 0ull) {
        const int   n   = __popcll(ball);
        const float em1 = expf(-1.0f);
        const float denom = (float)n + (float)(EXPERTS - n) * em1;
        out = spike ? (1.0f / denom) : (em1 / denom);
    } else {
        float m = v;
#pragma unroll
        for (int off = 32; off >= 1; off >>= 1)
            m = fmaxf(m, __shfl_xor(m, off, 64));
        const float p = expf(v - m);
        float s = p;
#pragma unroll
        for (int off = 32; off >= 1; off >>= 1)
            s += __shfl_xor(s, off, 64);
        out = p / s;
    }
    io[t * EXPERTS + lane] = out;
}

// ---------------------------------------------------------------------------
extern "C" void kernel_launch(void* const* d_in, const int* in_sizes, int n_in,
                              void* d_out, int out_size, void* d_ws, size_t ws_size,
                              hipStream_t stream) {
    const float* hs = (const float*)d_in[0];   // [4,2048,2048] f32
    const float* w  = (const float*)d_in[1];   // [2048,64] f32
    float* out = (float*)d_out;                // [4,2048,64] f32

    char*  ws     = (char*)d_ws;
    int*   flags  = (int*)ws;                  // KITER*NCHUNK ints (256 B)
    float* states = (float*)(ws + 4096);       // KITER*NCHUNK*128 floats (32 KB)
    float* cur    = (float*)(ws + 65536);      // 8192*64 floats (2 MB)

    hipMemsetAsync(flags, 0, KITER * NCHUNK * sizeof(int), stream);
    snn_gemm<<<dim3(T_TOTAL / GBLK_ROWS), dim3(256), 0, stream>>>(hs, w, cur);
    snn_scan_wfr<<<dim3(NCHUNK), dim3(64), 0, stream>>>(cur, out, states, flags);
    snn_softmax<<<dim3(T_TOTAL / 4), dim3(256), 0, stream>>>(out);
}

// Round 3
// 195.969 us; speedup vs baseline: 2.1440x; 1.1294x over previous
//
#include <hip/hip_runtime.h>

#define HIDDEN 2048
#define EXPERTS 64
#define T_TOTAL 8192

// ================= GEMM: split-K LDS-tiled vector fp32 =================
#define BM 256
#define BK 32
#define LDA 36   // padded words/row: 16B-aligned; 8 rows/read-instr hit distinct bank groups

__global__ __launch_bounds__(256, 1) void snn_gemm_sk(
        const float* __restrict__ A, const float* __restrict__ W,
        float* __restrict__ P, int KS) {
    __shared__ float As[2][BM * LDA];        // 72 KB
    __shared__ float Ws[2][BK * EXPERTS];    // 16 KB

    const int t  = threadIdx.x;
    const int tc = t & 7;          // expert group: experts tc*8 .. tc*8+7
    const int tr = t >> 3;         // 0..31 ; rows tr + 32j, j=0..7
    const long row0 = (long)blockIdx.x * BM;
    const int  k0   = blockIdx.y * KS;
    float* Pout = P + (long)blockIdx.y * ((long)T_TOTAL * EXPERTS);

    const int rs = t >> 3;         // staging row
    const int kq = t & 7;          // staging k-quad

    float acc[8][8];
#pragma unroll
    for (int j = 0; j < 8; ++j)
#pragma unroll
        for (int i = 0; i < 8; ++i) acc[j][i] = 0.0f;

    float4 ar[8];
    float4 wr[2];

    auto stage_load = [&](int k) {
#pragma unroll
        for (int p = 0; p < 8; ++p)
            ar[p] = *reinterpret_cast<const float4*>(
                &A[(row0 + rs + 32 * p) * HIDDEN + k + kq * 4]);
#pragma unroll
        for (int p = 0; p < 2; ++p)
            wr[p] = *reinterpret_cast<const float4*>(
                &W[(long)k * EXPERTS + (t + 256 * p) * 4]);
    };
    auto stage_write = [&](int buf) {
        float* ab = &As[buf][0];
#pragma unroll
        for (int p = 0; p < 8; ++p)
            *reinterpret_cast<float4*>(&ab[(rs + 32 * p) * LDA + kq * 4]) = ar[p];
        float* wb = &Ws[buf][0];
#pragma unroll
        for (int p = 0; p < 2; ++p)
            *reinterpret_cast<float4*>(&wb[(t + 256 * p) * 4]) = wr[p];
    };

    stage_load(k0);
    stage_write(0);
    __syncthreads();

    const int ntile = KS / BK;
    for (int tile = 0; tile < ntile; ++tile) {
        const int buf = tile & 1;
        if (tile + 1 < ntile) stage_load(k0 + (tile + 1) * BK);   // issue early

        const float* ab = &As[buf][0];
        const float* wb = &Ws[buf][0];
#pragma unroll
        for (int q = 0; q < BK / 4; ++q) {
            float4 a4[8];
            float4 w4[4][2];
#pragma unroll
            for (int j = 0; j < 8; ++j)
                a4[j] = *reinterpret_cast<const float4*>(
                    &ab[(tr + 32 * j) * LDA + q * 4]);
#pragma unroll
            for (int ki = 0; ki < 4; ++ki)
#pragma unroll
                for (int i = 0; i < 2; ++i)
                    w4[ki][i] = *reinterpret_cast<const float4*>(
                        &wb[(q * 4 + ki) * EXPERTS + tc * 8 + i * 4]);
            // k ascending within quad -> each acc[j][i] sums k in pure ascending order
#pragma unroll
            for (int j = 0; j < 8; ++j)
#pragma unroll
                for (int ki = 0; ki < 4; ++ki) {
                    const float av = (&a4[j].x)[ki];
#pragma unroll
                    for (int i = 0; i < 8; ++i)
                        acc[j][i] = fmaf(av, (&w4[ki][i >> 2].x)[i & 3], acc[j][i]);
                }
        }
        if (tile + 1 < ntile) stage_write(buf ^ 1);   // vmcnt wait hidden by compute
        __syncthreads();
    }

#pragma unroll
    for (int j = 0; j < 8; ++j) {
        float* base = &Pout[(row0 + tr + 32 * j) * EXPERTS + tc * 8];
        *reinterpret_cast<float4*>(base) =
            make_float4(acc[j][0], acc[j][1], acc[j][2], acc[j][3]);
        *reinterpret_cast<float4*>(base + 4) =
            make_float4(acc[j][4], acc[j][5], acc[j][6], acc[j][7]);
    }
}

// ---- fixed-order split-K combine: cur = ((p0+p1)+p2)+... ----
__global__ __launch_bounds__(256) void snn_combine(const float* __restrict__ P,
                                                   float* __restrict__ cur, int nsplit) {
    const long i = (long)blockIdx.x * 256 + threadIdx.x;   // float4 index
    const float4* p = reinterpret_cast<const float4*>(P);
    float4 s = p[i];
    for (int k = 1; k < nsplit; ++k) {
        const float4 v = p[i + (long)k * (T_TOTAL * EXPERTS / 4)];
        s.x += v.x; s.y += v.y; s.z += v.z; s.w += v.w;
    }
    reinterpret_cast<float4*>(cur)[i] = s;
}

// ================= Scan: waveform relaxation, 32 chunks x 256 steps =================
#define NCHUNK 32
#define CSTEPS (T_TOTAL / NCHUNK)   // 256
#define KITER  4
#define PF     32

__global__ __launch_bounds__(64) void snn_scan_wfr(const float* __restrict__ cur,
                                                   float* __restrict__ mp_out,
                                                   float* __restrict__ states,
                                                   int* __restrict__ flags) {
#pragma clang fp contract(off)
    __shared__ float smp[CSTEPS * EXPERTS];   // 64 KB
    const int e = threadIdx.x;
    const int w = blockIdx.x;
    const float* cbase = cur + (long)w * CSTEPS * EXPERTS + e;

    for (int k = 1; k <= KITER; ++k) {
        float mp = 0.0f, refr = 0.0f;
        if (w > 0 && k > 1) {
            const int s = (k - 2) * NCHUNK + (w - 1);
            if (e == 0) {
                while (__hip_atomic_load(&flags[s], __ATOMIC_ACQUIRE, __HIP_MEMORY_SCOPE_AGENT) == 0)
                    __builtin_amdgcn_s_sleep(8);
            }
            __threadfence();
            mp   = __hip_atomic_load(&states[s * 2 * EXPERTS + e], __ATOMIC_RELAXED, __HIP_MEMORY_SCOPE_AGENT);
            refr = __hip_atomic_load(&states[s * 2 * EXPERTS + EXPERTS + e], __ATOMIC_RELAXED, __HIP_MEMORY_SCOPE_AGENT);
        }

        float ca[PF], cb[PF];
#pragma unroll
        for (int j = 0; j < PF; ++j) ca[j] = cbase[j * EXPERTS] * 0.1f;

        for (int t0 = 0; t0 < CSTEPS; t0 += 2 * PF) {
#pragma unroll
            for (int j = 0; j < PF; ++j) cb[j] = cbase[(t0 + PF + j) * EXPERTS] * 0.1f;
#pragma unroll
            for (int j = 0; j < PF; ++j) {
                const float term   = (refr <= 0.0f) ? ca[j] : 0.0f;
                const float mp_pre = mp * 0.9f + term;
                smp[(t0 + j) * EXPERTS + e] = mp_pre;
                const bool spike = mp_pre > 1.0f;
                mp = spike ? 0.0f : mp_pre;
                const float rdec = fmaxf(refr - 0.1f, 0.0f);
                refr = spike ? 1.0f : rdec;
            }
            if (t0 + 2 * PF < CSTEPS) {
#pragma unroll
                for (int j = 0; j < PF; ++j) ca[j] = cbase[(t0 + 2 * PF + j) * EXPERTS] * 0.1f;
            }
#pragma unroll
            for (int j = 0; j < PF; ++j) {
                const float term   = (refr <= 0.0f) ? cb[j] : 0.0f;
                const float mp_pre = mp * 0.9f + term;
                smp[(t0 + PF + j) * EXPERTS + e] = mp_pre;
                const bool spike = mp_pre > 1.0f;
                mp = spike ? 0.0f : mp_pre;
                const float rdec = fmaxf(refr - 0.1f, 0.0f);
                refr = spike ? 1.0f : rdec;
            }
        }

        if (k < KITER && w < NCHUNK - 1) {
            const int s2 = (k - 1) * NCHUNK + w;
            __hip_atomic_store(&states[s2 * 2 * EXPERTS + e], mp, __ATOMIC_RELAXED, __HIP_MEMORY_SCOPE_AGENT);
            __hip_atomic_store(&states[s2 * 2 * EXPERTS + EXPERTS + e], refr, __ATOMIC_RELAXED, __HIP_MEMORY_SCOPE_AGENT);
            __threadfence();
            if (e == 0)
                __hip_atomic_store(&flags[s2], 1, __ATOMIC_RELEASE, __HIP_MEMORY_SCOPE_AGENT);
        }
    }

    float4* o4 = reinterpret_cast<float4*>(mp_out + (long)w * CSTEPS * EXPERTS);
    const float4* s4 = reinterpret_cast<const float4*>(smp);
#pragma unroll 4
    for (int i = threadIdx.x; i < CSTEPS * EXPERTS / 4; i += 64)
        o4[i] = s4[i];
}

// ================= Routing softmax (in-place on d_out) =================
__global__ __launch_bounds__(256) void snn_softmax(float* __restrict__ io) {
    const int  lane = threadIdx.x & 63;
    const int  wv   = threadIdx.x >> 6;
    const long t    = (long)blockIdx.x * 4 + wv;

    const float v = io[t * EXPERTS + lane];
    const bool spike = v > 1.0f;
    const unsigned long long ball = __ballot(spike);

    float out;
    if (ball != 0ull) {
        const int   n   = __popcll(ball);
        const float em1 = expf(-1.0f);
        const float denom = (float)n + (float)(EXPERTS - n) * em1;
        out = spike ? (1.0f / denom) : (em1 / denom);
    } else {
        float m = v;
#pragma unroll
        for (int off = 32; off >= 1; off >>= 1)
            m = fmaxf(m, __shfl_xor(m, off, 64));
        const float p = expf(v - m);
        float s = p;
#pragma unroll
        for (int off = 32; off >= 1; off >>= 1)
            s += __shfl_xor(s, off, 64);
        out = p / s;
    }
    io[t * EXPERTS + lane] = out;
}

// ---------------------------------------------------------------------------
extern "C" void kernel_launch(void* const* d_in, const int* in_sizes, int n_in,
                              void* d_out, int out_size, void* d_ws, size_t ws_size,
                              hipStream_t stream) {
    const float* hs = (const float*)d_in[0];   // [4,2048,2048] f32
    const float* w  = (const float*)d_in[1];   // [2048,64] f32
    float* out = (float*)d_out;                // [4,2048,64] f32

    char*  ws     = (char*)d_ws;
    int*   flags  = (int*)ws;                          // 4 KB
    float* states = (float*)(ws + 4096);               // 64 KB
    float* cur    = (float*)(ws + (1u << 20));         // 2 MB  @ 1 MB
    float* part   = (float*)(ws + (4u << 20));         // nsplit*2 MB @ 4 MB

    const size_t slab = (size_t)T_TOTAL * EXPERTS * sizeof(float);   // 2 MB
    int nsplit;
    if      (ws_size >= (4u << 20) + 8 * slab) nsplit = 8;   // 20 MB
    else if (ws_size >= (4u << 20) + 2 * slab) nsplit = 2;   // 8 MB
    else                                       nsplit = 1;

    hipMemsetAsync(flags, 0, 4096, stream);

    if (nsplit == 1) {
        snn_gemm_sk<<<dim3(T_TOTAL / BM, 1), dim3(256), 0, stream>>>(hs, w, cur, HIDDEN);
    } else {
        snn_gemm_sk<<<dim3(T_TOTAL / BM, nsplit), dim3(256), 0, stream>>>(hs, w, part, HIDDEN / nsplit);
        snn_combine<<<dim3(T_TOTAL * EXPERTS / 4 / 256), dim3(256), 0, stream>>>(part, cur, nsplit);
    }
    snn_scan_wfr<<<dim3(NCHUNK), dim3(64), 0, stream>>>(cur, out, states, flags);
    snn_softmax<<<dim3(T_TOTAL / 4), dim3(256), 0, stream>>>(out);
}